// Round 2
// baseline (89234.229 us; speedup 1.0000x reference)
//
#include <hip/hip_runtime.h>
#include <math.h>

#define T_STEPS 512
#define NL      5

typedef short bf16x8 __attribute__((ext_vector_type(8)));
typedef float f32x4  __attribute__((ext_vector_type(4)));

// ---- workspace layout (bytes) ----
#define OFF_P    0ull                         // [32768][1024] f32 = 134217728
#define OFF_W    134217728ull                 // 3 planes x 1048576 shorts
#define OFF_R    (OFF_W + 6291456ull)         // 3 planes x 2621440 shorts
#define OFF_WBC  (OFF_R + 15728640ull)        // [1024] f32
#define OFF_RBC  (OFF_WBC + 4096ull)          // [5][1024] f32
#define OFF_H    (OFF_RBC + 20480ull)         // 2 bufs x 3 planes x 32768 shorts
#define OFF_BAR  (OFF_H + 393216ull)          // 4

#define WPLANE 1048576      // shorts per W plane
#define RPLANE 2621440      // shorts per R plane
#define HPLANE 32768        // shorts per h plane
#define HBUFSTRIDE 98304    // shorts per h buffer (3 planes)

__device__ __forceinline__ unsigned bf_rne(float f) {
    unsigned u = __float_as_uint(f);
    unsigned r = u + 0x7FFFu + ((u >> 16) & 1u);
    return r >> 16;
}
__device__ __forceinline__ float bf_to_f(unsigned bits) {
    return __uint_as_float(bits << 16);
}
// 3-way bf16 split: f = s0 + s1 + s2 + O(2^-27 |f|)
__device__ __forceinline__ void split3(float f, short& s0, short& s1, short& s2) {
    unsigned b0 = bf_rne(f);
    float r1 = f - bf_to_f(b0);
    unsigned b1 = bf_rne(r1);
    float r2 = r1 - bf_to_f(b1);
    unsigned b2 = bf_rne(r2);
    s0 = (short)b0; s1 = (short)b1; s2 = (short)b2;
}
__device__ __forceinline__ float fast_sigmoid(float x) { return 1.0f / (1.0f + __expf(-x)); }
__device__ __forceinline__ float fast_tanh(float x)    { return 2.0f / (1.0f + __expf(-2.0f * x)) - 1.0f; }

// ---------------- prep: convert/transpose weights (split-3), zero state ----------------
__global__ void rhn_prep(const float* __restrict__ WHw, const float* __restrict__ WHb,
                         const float* __restrict__ WCw, const float* __restrict__ WCb,
                         const float* __restrict__ RHw, const float* __restrict__ RHb,
                         const float* __restrict__ RCw, const float* __restrict__ RCb,
                         short* __restrict__ Wt, short* __restrict__ Rt,
                         float* __restrict__ wbc, float* __restrict__ rbc,
                         short* __restrict__ hbuf, unsigned* __restrict__ bar)
{
    long long idx = (long long)blockIdx.x * blockDim.x + threadIdx.x;
    if (idx < WPLANE) {            // Wt[n][d] <- W[d][n] combined [H|C]
        int n = (int)(idx >> 10), d = (int)(idx & 1023);
        float v = (n < 512) ? WHw[d * 512 + n] : WCw[d * 512 + (n - 512)];
        short s0, s1, s2; split3(v, s0, s1, s2);
        Wt[idx] = s0; Wt[WPLANE + idx] = s1; Wt[2 * WPLANE + idx] = s2;
        return;
    }
    idx -= WPLANE;
    if (idx < RPLANE) {            // Rt[l][cc][k] <- R[l][k][cc]
        int l = (int)(idx >> 19);
        int rem = (int)(idx & 524287);
        int cc = rem >> 9, k = rem & 511;
        float v = (cc < 512) ? RHw[(l * 512 + k) * 512 + cc]
                             : RCw[(l * 512 + k) * 512 + (cc - 512)];
        short s0, s1, s2; split3(v, s0, s1, s2);
        Rt[idx] = s0; Rt[RPLANE + idx] = s1; Rt[2 * RPLANE + idx] = s2;
        return;
    }
    idx -= RPLANE;
    if (idx < 1024) { wbc[idx] = (idx < 512) ? WHb[idx] : WCb[idx - 512]; return; }
    idx -= 1024;
    if (idx < 5120) {
        int l = (int)(idx >> 10), c = (int)(idx & 1023);
        rbc[idx] = (c < 512) ? RHb[l * 512 + c] : RCb[l * 512 + (c - 512)];
        return;
    }
    idx -= 5120;
    if (idx < 2 * HBUFSTRIDE) { hbuf[idx] = 0; return; }
    idx -= 2 * HBUFSTRIDE;
    if (idx == 0) *bar = 0u;
}

// ---------------- projection: P = x @ [W_H | W_C] + bias (split-3, 6 terms) ----------------
__global__ void __launch_bounds__(256) rhn_proj(const float* __restrict__ x,
                                                const short* __restrict__ Wt,
                                                const float* __restrict__ wbc,
                                                float* __restrict__ P)
{
    const int bx = blockIdx.x;          // 0..15  (64-col tiles)
    const int by = blockIdx.y;          // 0..511 (64-row tiles)
    const int tid = threadIdx.x, wave = tid >> 6, lane = tid & 63;
    const int n = lane & 15, quad = lane >> 4;
    const int rowA = by * 64 + wave * 16 + n;    // A-frag row (m = lane&15)
    const float* xrow = x + (long long)rowA * 1024;

    f32x4 acc[4];
#pragma unroll
    for (int nt = 0; nt < 4; ++nt) {
        float b = wbc[bx * 64 + nt * 16 + n];
        acc[nt][0] = b; acc[nt][1] = b; acc[nt][2] = b; acc[nt][3] = b;
    }

    for (int ks = 0; ks < 32; ++ks) {
        const int ko = ks * 32 + quad * 8;
        f32x4 f0 = *(const f32x4*)(xrow + ko);
        f32x4 f1 = *(const f32x4*)(xrow + ko + 4);
        bf16x8 a0, a1, a2;
#pragma unroll
        for (int i = 0; i < 4; ++i) {
            short u0, u1, u2;
            split3(f0[i], u0, u1, u2);
            a0[i] = u0; a1[i] = u1; a2[i] = u2;
            split3(f1[i], u0, u1, u2);
            a0[4 + i] = u0; a1[4 + i] = u1; a2[4 + i] = u2;
        }
#pragma unroll
        for (int nt = 0; nt < 4; ++nt) {
            const long long wi = (long long)(bx * 64 + nt * 16 + n) * 1024 + ko;
            bf16x8 b0 = *(const bf16x8*)(Wt + wi);
            bf16x8 b1 = *(const bf16x8*)(Wt + WPLANE + wi);
            bf16x8 b2 = *(const bf16x8*)(Wt + 2 * WPLANE + wi);
            // small terms first
            acc[nt] = __builtin_amdgcn_mfma_f32_16x16x32_bf16(a2, b0, acc[nt], 0, 0, 0);
            acc[nt] = __builtin_amdgcn_mfma_f32_16x16x32_bf16(a1, b1, acc[nt], 0, 0, 0);
            acc[nt] = __builtin_amdgcn_mfma_f32_16x16x32_bf16(a0, b2, acc[nt], 0, 0, 0);
            acc[nt] = __builtin_amdgcn_mfma_f32_16x16x32_bf16(a1, b0, acc[nt], 0, 0, 0);
            acc[nt] = __builtin_amdgcn_mfma_f32_16x16x32_bf16(a0, b1, acc[nt], 0, 0, 0);
            acc[nt] = __builtin_amdgcn_mfma_f32_16x16x32_bf16(a0, b0, acc[nt], 0, 0, 0);
        }
    }
#pragma unroll
    for (int nt = 0; nt < 4; ++nt)
#pragma unroll
        for (int r = 0; r < 4; ++r)
            P[(long long)(by * 64 + wave * 16 + quad * 4 + r) * 1024 + bx * 64 + nt * 16 + n] = acc[nt][r];
}

// ---------------- persistent recurrent kernel ----------------
// 64 WGs x 256 threads (4 waves). WG g owns hidden cols [8g, 8g+8).
// N-tile (16): lanes n<8 -> H-gate col jbase+n ; n>=8 -> C-gate (combined col +512).
// Wave w = M-tile rows [16w, 16w+16). Split-3 bf16, 6 MFMA terms, 3 interleaved accs.
__global__ void __launch_bounds__(256, 1) rhn_rec(const float* __restrict__ P,
                                                  const short* __restrict__ Rt,
                                                  const float* __restrict__ rbc,
                                                  short* __restrict__ hbuf,
                                                  float* __restrict__ out,
                                                  unsigned* __restrict__ bar)
{
    const int wg = blockIdx.x;          // 0..63
    const int tid = threadIdx.x;
    const int wave = tid >> 6;
    const int lane = tid & 63;
    const int n = lane & 15;
    const int quad = lane >> 4;
    const int jbase = wg * 8;
    const bool isH = (n < 8);
    const int ccol = isH ? (jbase + n) : (512 + jbase + (n - 8));
    const int arow = wave * 16 + n;           // A-frag row (batch)
    const int wrow = wave * 16 + quad * 4;    // D rows base (+r)
    const int jcol = jbase + (n & 7);         // owned col (valid on isH lanes)

    float hold[4] = {0.f, 0.f, 0.f, 0.f};     // exact f32 hidden (isH lanes)
    float* hidOut = out + 33554432;           // hiddens region [64][1024]

    float rb[NL];
#pragma unroll
    for (int l = 0; l < NL; ++l) rb[l] = rbc[l * 1024 + ccol];

    unsigned stage = 0;
    for (int step = 0; step < 2 * T_STEPS; ++step) {
        const int pass = (step >= T_STEPS) ? 1 : 0;
        const int t = step - pass * T_STEPS;
        const float* Pt = P + (long long)t * (64 * 1024);
#pragma unroll
        for (int l = 0; l < NL; ++l) {
            const short* hr = hbuf + (stage & 1u) * HBUFSTRIDE;
            short* hw = hbuf + ((stage & 1u) ^ 1u) * HBUFSTRIDE;

            f32x4 acc0, acc1, acc2;
            {
                float b0 = rb[l];
                acc0[0] = b0; acc0[1] = b0; acc0[2] = b0; acc0[3] = b0;
                acc1[0] = 0.f; acc1[1] = 0.f; acc1[2] = 0.f; acc1[3] = 0.f;
                acc2[0] = 0.f; acc2[1] = 0.f; acc2[2] = 0.f; acc2[3] = 0.f;
            }
            if (l == 0) {
#pragma unroll
                for (int r = 0; r < 4; ++r)
                    acc0[r] += Pt[(wrow + r) * 1024 + ccol];
            }
            const short* bp = Rt + ((l * 1024 + ccol) << 9) + quad * 8;
            const short* ap = hr + (arow << 9) + quad * 8;
#pragma unroll 4
            for (int ks = 0; ks < 16; ++ks) {
                const int o = ks * 32;
                bf16x8 a0 = *(const bf16x8*)(ap + o);
                bf16x8 a1 = *(const bf16x8*)(ap + HPLANE + o);
                bf16x8 a2 = *(const bf16x8*)(ap + 2 * HPLANE + o);
                bf16x8 b0 = *(const bf16x8*)(bp + o);
                bf16x8 b1 = *(const bf16x8*)(bp + RPLANE + o);
                bf16x8 b2 = *(const bf16x8*)(bp + 2 * RPLANE + o);
                acc0 = __builtin_amdgcn_mfma_f32_16x16x32_bf16(a0, b0, acc0, 0, 0, 0);
                acc1 = __builtin_amdgcn_mfma_f32_16x16x32_bf16(a1, b0, acc1, 0, 0, 0);
                acc2 = __builtin_amdgcn_mfma_f32_16x16x32_bf16(a2, b0, acc2, 0, 0, 0);
                acc0 = __builtin_amdgcn_mfma_f32_16x16x32_bf16(a0, b1, acc0, 0, 0, 0);
                acc1 = __builtin_amdgcn_mfma_f32_16x16x32_bf16(a1, b1, acc1, 0, 0, 0);
                acc2 = __builtin_amdgcn_mfma_f32_16x16x32_bf16(a0, b2, acc2, 0, 0, 0);
            }
            // activation + gate exchange + highway mix + state write
#pragma unroll
            for (int r = 0; r < 4; ++r) {
                float p = (acc2[r] + acc1[r]) + acc0[r];   // small-to-large
                float a = isH ? fast_tanh(p) : fast_sigmoid(p);
                float o = __shfl_xor(a, 8, 64);
                if (isH) {
                    float tl = o;
                    float hn = a * tl + hold[r] * (1.0f - tl);
                    hold[r] = hn;
                    const int row = wrow + r;
                    short s0, s1, s2; split3(hn, s0, s1, s2);
                    hw[(row << 9) + jcol] = s0;
                    hw[HPLANE + (row << 9) + jcol] = s1;
                    hw[2 * HPLANE + (row << 9) + jcol] = s2;
                    if (l == NL - 1) {
                        out[(long long)(t * 64 + row) * 1024 + pass * 512 + jcol] = hn;
                        if (t == T_STEPS - 1)
                            hidOut[row * 1024 + pass * 512 + jcol] = hn;
                    }
                }
            }
            // ---- grid barrier (64 WGs co-resident via cooperative launch) ----
            ++stage;
            __syncthreads();   // includes vmcnt(0): h stores complete (in L2)
            if (tid == 0) {
                // release-add: flushes this XCD's dirty L2 lines to coherent point
                __hip_atomic_fetch_add(bar, 1u, __ATOMIC_RELEASE, __HIP_MEMORY_SCOPE_AGENT);
                const unsigned tgt = stage * 64u;
                while (__hip_atomic_load(bar, __ATOMIC_RELAXED, __HIP_MEMORY_SCOPE_AGENT) < tgt) {
                    __builtin_amdgcn_s_sleep(2);
                }
            }
            __syncthreads();
            __builtin_amdgcn_fence(__ATOMIC_ACQUIRE, "agent");  // invalidate stale caches
        }
    }
}

extern "C" void kernel_launch(void* const* d_in, const int* in_sizes, int n_in,
                              void* d_out, int out_size, void* d_ws, size_t ws_size,
                              hipStream_t stream)
{
    const float* x   = (const float*)d_in[0];
    const float* WHw = (const float*)d_in[1];
    const float* WHb = (const float*)d_in[2];
    const float* WCw = (const float*)d_in[3];
    const float* WCb = (const float*)d_in[4];
    const float* RHw = (const float*)d_in[5];
    const float* RHb = (const float*)d_in[6];
    const float* RCw = (const float*)d_in[7];
    const float* RCb = (const float*)d_in[8];

    char* ws = (char*)d_ws;
    float*    Pbuf = (float*)(ws + OFF_P);
    short*    Wt   = (short*)(ws + OFF_W);
    short*    Rt   = (short*)(ws + OFF_R);
    float*    wbc  = (float*)(ws + OFF_WBC);
    float*    rbc  = (float*)(ws + OFF_RBC);
    short*    hbuf = (short*)(ws + OFF_H);
    unsigned* bar  = (unsigned*)(ws + OFF_BAR);
    float*    outp = (float*)d_out;

    rhn_prep<<<15129, 256, 0, stream>>>(WHw, WHb, WCw, WCb, RHw, RHb, RCw, RCb,
                                        Wt, Rt, wbc, rbc, hbuf, bar);
    rhn_proj<<<dim3(16, 512), 256, 0, stream>>>(x, Wt, wbc, Pbuf);

    void* args[] = {&Pbuf, &Rt, &rbc, &hbuf, &outp, &bar};
    hipLaunchCooperativeKernel(reinterpret_cast<void*>(rhn_rec), dim3(64), dim3(256),
                               args, 0, stream);
}

// Round 3
// 43363.876 us; speedup vs baseline: 2.0578x; 2.0578x over previous
//
#include <hip/hip_runtime.h>
#include <math.h>

#define T_STEPS 512
#define NL      5

typedef short bf16x8 __attribute__((ext_vector_type(8)));
typedef float f32x4  __attribute__((ext_vector_type(4)));

// ---- workspace layout (bytes) ----
#define OFF_P     0ull                         // [32768][1024] f32 = 134217728
#define OFF_W     134217728ull                 // 3 planes x 1048576 shorts
#define OFF_R     (OFF_W + 6291456ull)         // 3 planes x 2621440 shorts
#define OFF_WBC   (OFF_R + 15728640ull)        // [1024] f32
#define OFF_RBC   (OFF_WBC + 4096ull)          // [5][1024] f32
#define OFF_H     (OFF_RBC + 20480ull)         // 2 bufs x [4 rg][3 plane][16][512] shorts
#define OFF_FLAGS (OFF_H + 393216ull)          // 64 x 16 u32 (64B-padded flags)

#define WPLANE 1048576      // shorts per W plane
#define RPLANE 2621440      // shorts per R plane
#define HBUFSTRIDE 98304    // shorts per h buffer  (4 rg x 3 planes x 16 x 512)
#define RGSLICE 24576       // shorts per row-group slice (3 x 16 x 512)

__device__ __forceinline__ unsigned bf_rne(float f) {
    unsigned u = __float_as_uint(f);
    unsigned r = u + 0x7FFFu + ((u >> 16) & 1u);
    return r >> 16;
}
__device__ __forceinline__ float bf_to_f(unsigned bits) {
    return __uint_as_float(bits << 16);
}
// 3-way bf16 split: f = s0 + s1 + s2 + O(2^-27 |f|)
__device__ __forceinline__ void split3(float f, short& s0, short& s1, short& s2) {
    unsigned b0 = bf_rne(f);
    float r1 = f - bf_to_f(b0);
    unsigned b1 = bf_rne(r1);
    float r2 = r1 - bf_to_f(b1);
    unsigned b2 = bf_rne(r2);
    s0 = (short)b0; s1 = (short)b1; s2 = (short)b2;
}
__device__ __forceinline__ float fast_sigmoid(float x) { return 1.0f / (1.0f + __expf(-x)); }
__device__ __forceinline__ float fast_tanh(float x)    { return 2.0f / (1.0f + __expf(-2.0f * x)) - 1.0f; }

// ---------------- prep: convert/transpose weights (split-3), zero state ----------------
__global__ void rhn_prep(const float* __restrict__ WHw, const float* __restrict__ WHb,
                         const float* __restrict__ WCw, const float* __restrict__ WCb,
                         const float* __restrict__ RHw, const float* __restrict__ RHb,
                         const float* __restrict__ RCw, const float* __restrict__ RCb,
                         short* __restrict__ Wt, short* __restrict__ Rt,
                         float* __restrict__ wbc, float* __restrict__ rbc,
                         short* __restrict__ hbuf, unsigned* __restrict__ flags)
{
    long long idx = (long long)blockIdx.x * blockDim.x + threadIdx.x;
    if (idx < WPLANE) {            // Wt[n][d] <- W[d][n] combined [H|C]
        int n = (int)(idx >> 10), d = (int)(idx & 1023);
        float v = (n < 512) ? WHw[d * 512 + n] : WCw[d * 512 + (n - 512)];
        short s0, s1, s2; split3(v, s0, s1, s2);
        Wt[idx] = s0; Wt[WPLANE + idx] = s1; Wt[2 * WPLANE + idx] = s2;
        return;
    }
    idx -= WPLANE;
    if (idx < RPLANE) {            // Rt[l][cc][k] <- R[l][k][cc]
        int l = (int)(idx >> 19);
        int rem = (int)(idx & 524287);
        int cc = rem >> 9, k = rem & 511;
        float v = (cc < 512) ? RHw[(l * 512 + k) * 512 + cc]
                             : RCw[(l * 512 + k) * 512 + (cc - 512)];
        short s0, s1, s2; split3(v, s0, s1, s2);
        Rt[idx] = s0; Rt[RPLANE + idx] = s1; Rt[2 * RPLANE + idx] = s2;
        return;
    }
    idx -= RPLANE;
    if (idx < 1024) { wbc[idx] = (idx < 512) ? WHb[idx] : WCb[idx - 512]; return; }
    idx -= 1024;
    if (idx < 5120) {
        int l = (int)(idx >> 10), c = (int)(idx & 1023);
        rbc[idx] = (c < 512) ? RHb[l * 512 + c] : RCb[l * 512 + (c - 512)];
        return;
    }
    idx -= 5120;
    if (idx < 2 * HBUFSTRIDE) { hbuf[idx] = 0; return; }
    idx -= 2 * HBUFSTRIDE;
    if (idx < 1024) { flags[idx] = 0u; return; }
}

// ---------------- projection: P = x @ [W_H | W_C] + bias (split-3, 6 terms) ----------------
__global__ void __launch_bounds__(256) rhn_proj(const float* __restrict__ x,
                                                const short* __restrict__ Wt,
                                                const float* __restrict__ wbc,
                                                float* __restrict__ P)
{
    const int bx = blockIdx.x;          // 0..15  (64-col tiles)
    const int by = blockIdx.y;          // 0..511 (64-row tiles)
    const int tid = threadIdx.x, wave = tid >> 6, lane = tid & 63;
    const int n = lane & 15, quad = lane >> 4;
    const int rowA = by * 64 + wave * 16 + n;    // A-frag row (m = lane&15)
    const float* xrow = x + (long long)rowA * 1024;

    f32x4 acc[4];
#pragma unroll
    for (int nt = 0; nt < 4; ++nt) {
        float b = wbc[bx * 64 + nt * 16 + n];
        acc[nt][0] = b; acc[nt][1] = b; acc[nt][2] = b; acc[nt][3] = b;
    }

    for (int ks = 0; ks < 32; ++ks) {
        const int ko = ks * 32 + quad * 8;
        f32x4 f0 = *(const f32x4*)(xrow + ko);
        f32x4 f1 = *(const f32x4*)(xrow + ko + 4);
        bf16x8 a0, a1, a2;
#pragma unroll
        for (int i = 0; i < 4; ++i) {
            short u0, u1, u2;
            split3(f0[i], u0, u1, u2);
            a0[i] = u0; a1[i] = u1; a2[i] = u2;
            split3(f1[i], u0, u1, u2);
            a0[4 + i] = u0; a1[4 + i] = u1; a2[4 + i] = u2;
        }
#pragma unroll
        for (int nt = 0; nt < 4; ++nt) {
            const long long wi = (long long)(bx * 64 + nt * 16 + n) * 1024 + ko;
            bf16x8 b0 = *(const bf16x8*)(Wt + wi);
            bf16x8 b1 = *(const bf16x8*)(Wt + WPLANE + wi);
            bf16x8 b2 = *(const bf16x8*)(Wt + 2 * WPLANE + wi);
            acc[nt] = __builtin_amdgcn_mfma_f32_16x16x32_bf16(a2, b0, acc[nt], 0, 0, 0);
            acc[nt] = __builtin_amdgcn_mfma_f32_16x16x32_bf16(a1, b1, acc[nt], 0, 0, 0);
            acc[nt] = __builtin_amdgcn_mfma_f32_16x16x32_bf16(a0, b2, acc[nt], 0, 0, 0);
            acc[nt] = __builtin_amdgcn_mfma_f32_16x16x32_bf16(a1, b0, acc[nt], 0, 0, 0);
            acc[nt] = __builtin_amdgcn_mfma_f32_16x16x32_bf16(a0, b1, acc[nt], 0, 0, 0);
            acc[nt] = __builtin_amdgcn_mfma_f32_16x16x32_bf16(a0, b0, acc[nt], 0, 0, 0);
        }
    }
#pragma unroll
    for (int nt = 0; nt < 4; ++nt)
#pragma unroll
        for (int r = 0; r < 4; ++r)
            P[(long long)(by * 64 + wave * 16 + quad * 4 + r) * 1024 + bx * 64 + nt * 16 + n] = acc[nt][r];
}

// ---------------- persistent recurrent kernel ----------------
// 64 WGs = 4 row-groups (16 batch rows each) x 16 col-groups (32 H-cols each).
// Row-groups are fully independent (batch rows don't interact) -> per-group
// 16-WG flag barrier. h exchanged via agent-coherent atomics (no fences, L2
// for weights never invalidated). h slice staged to LDS once per stage.
__global__ void __launch_bounds__(256, 1) rhn_rec(const float* __restrict__ P,
                                                  const short* __restrict__ Rt,
                                                  const float* __restrict__ rbc,
                                                  short* __restrict__ hbuf,
                                                  unsigned* __restrict__ flags,
                                                  float* __restrict__ out)
{
    __shared__ short hsm[24960];        // [3 planes][16 rows][520] (pad 8 shorts/row)
    const int wg = blockIdx.x;          // 0..63
    const int rg = wg >> 4;             // row-group 0..3
    const int cg = wg & 15;             // col-group 0..15
    const int tid = threadIdx.x;
    const int wave = tid >> 6;
    const int lane = tid & 63;
    const int n = lane & 15;
    const int quad = lane >> 4;
    const bool isH = (n < 8);
    const int jH = cg * 32 + wave * 8 + (n & 7);   // owned H-col (0..511)
    const int ccol = isH ? jH : (512 + jH);        // combined col for B/bias
    const int rowloc = quad * 4;                   // local D-row base (+r)
    const int grow = rg * 16 + rowloc;             // global batch row base (+r)
    const int aoff = n * 520 + quad * 8;           // LDS A-frag offset (shorts)

    float hold[4] = {0.f, 0.f, 0.f, 0.f};          // exact f32 hidden (isH lanes)
    float* hidOut = out + 33554432;                // hiddens region [64][1024]
    unsigned* const myflag = flags + (wg << 4);    // 64B-padded
    const unsigned* const gflags = flags + (rg << 8);  // this group's 16 flags

    unsigned stage = 0;
#pragma unroll 1
    for (int step = 0; step < 2 * T_STEPS; ++step) {
        const int pass = (step >= T_STEPS) ? 1 : 0;
        const int t = step - pass * T_STEPS;
        const float* Pt = P + (long long)t * (64 * 1024);
#pragma unroll 1
        for (int l = 0; l < NL; ++l) {
            // ---- stage this row-group's h slice into LDS (agent-coherent reads) ----
            {
                const unsigned long long* hsrc = (const unsigned long long*)
                    (hbuf + (stage & 1u) * HBUFSTRIDE + rg * RGSLICE);
                unsigned long long v[24];
#pragma unroll
                for (int it = 0; it < 24; ++it)
                    v[it] = __hip_atomic_load(hsrc + (it * 256 + tid),
                                              __ATOMIC_RELAXED, __HIP_MEMORY_SCOPE_AGENT);
#pragma unroll
                for (int it = 0; it < 24; ++it) {
                    const int c = it * 256 + tid;             // u64 chunk (6144 total)
                    const int p = c >> 11, r = (c >> 7) & 15, k4 = c & 127;
                    *(unsigned long long*)&hsm[(p * 16 + r) * 520 + k4 * 4] = v[it];
                }
            }
            __syncthreads();

            // ---- GEMM: acc = bias (+P) + h @ R  (split-3, 6 MFMA terms) ----
            f32x4 acc0, acc1, acc2;
            {
                float b0 = rbc[l * 1024 + ccol];
                acc0[0] = b0; acc0[1] = b0; acc0[2] = b0; acc0[3] = b0;
                acc1[0] = 0.f; acc1[1] = 0.f; acc1[2] = 0.f; acc1[3] = 0.f;
                acc2[0] = 0.f; acc2[1] = 0.f; acc2[2] = 0.f; acc2[3] = 0.f;
            }
            if (l == 0) {
#pragma unroll
                for (int r = 0; r < 4; ++r)
                    acc0[r] += Pt[(grow + r) * 1024 + ccol];
            }
            const short* bp = Rt + ((l * 1024 + ccol) << 9) + quad * 8;
#pragma unroll
            for (int ks = 0; ks < 16; ++ks) {
                const int o = ks * 32;
                bf16x8 a0 = *(const bf16x8*)&hsm[aoff + o];
                bf16x8 a1 = *(const bf16x8*)&hsm[8320 + aoff + o];
                bf16x8 a2 = *(const bf16x8*)&hsm[16640 + aoff + o];
                bf16x8 b0 = *(const bf16x8*)(bp + o);
                bf16x8 b1 = *(const bf16x8*)(bp + RPLANE + o);
                bf16x8 b2 = *(const bf16x8*)(bp + 2 * RPLANE + o);
                acc0 = __builtin_amdgcn_mfma_f32_16x16x32_bf16(a0, b0, acc0, 0, 0, 0);
                acc1 = __builtin_amdgcn_mfma_f32_16x16x32_bf16(a1, b0, acc1, 0, 0, 0);
                acc2 = __builtin_amdgcn_mfma_f32_16x16x32_bf16(a2, b0, acc2, 0, 0, 0);
                acc0 = __builtin_amdgcn_mfma_f32_16x16x32_bf16(a0, b1, acc0, 0, 0, 0);
                acc1 = __builtin_amdgcn_mfma_f32_16x16x32_bf16(a1, b1, acc1, 0, 0, 0);
                acc2 = __builtin_amdgcn_mfma_f32_16x16x32_bf16(a0, b2, acc2, 0, 0, 0);
            }

            // ---- activation + gate exchange + highway mix ----
            float hn[4];
#pragma unroll
            for (int r = 0; r < 4; ++r) {
                float p = (acc2[r] + acc1[r]) + acc0[r];   // small-to-large
                float a = isH ? fast_tanh(p) : fast_sigmoid(p);
                float o = __shfl_xor(a, 8, 64);
                hn[r] = a * o + hold[r] * (1.0f - o);      // valid on isH lanes
            }
            if (isH) {
                unsigned pk[3][4];
#pragma unroll
                for (int r = 0; r < 4; ++r) {
                    hold[r] = hn[r];
                    short s0, s1, s2; split3(hn[r], s0, s1, s2);
                    pk[0][r] = (unsigned short)s0;
                    pk[1][r] = (unsigned short)s1;
                    pk[2][r] = (unsigned short)s2;
                }
                // pack neighbor col (n^1) into high half -> 4B coherent stores
#pragma unroll
                for (int p2 = 0; p2 < 3; ++p2)
#pragma unroll
                    for (int r = 0; r < 4; ++r) {
                        unsigned nb = __shfl_xor(pk[p2][r], 1, 64);
                        pk[p2][r] |= (nb << 16);
                    }
                if (!(n & 1)) {
                    unsigned* hwU = (unsigned*)hbuf + ((stage & 1u) ^ 1u) * 49152
                                    + rg * 12288 + (jH >> 1);
#pragma unroll
                    for (int p2 = 0; p2 < 3; ++p2)
#pragma unroll
                        for (int r = 0; r < 4; ++r)
                            __hip_atomic_store(hwU + p2 * 4096 + (rowloc + r) * 256,
                                               pk[p2][r], __ATOMIC_RELAXED,
                                               __HIP_MEMORY_SCOPE_AGENT);
                }
                if (l == NL - 1) {
#pragma unroll
                    for (int r = 0; r < 4; ++r) {
                        out[(long long)(t * 64 + grow + r) * 1024 + pass * 512 + jH] = hn[r];
                        if (t == T_STEPS - 1)
                            hidOut[(grow + r) * 1024 + pass * 512 + jH] = hn[r];
                    }
                }
            }

            // ---- row-group barrier: per-WG epoch flags, no RMW, no fences ----
            ++stage;
            __syncthreads();   // all waves drained (vmcnt(0)): h stores at coherent point
            if (tid == 0)
                __hip_atomic_store(myflag, stage, __ATOMIC_RELAXED, __HIP_MEMORY_SCOPE_AGENT);
            bool done = false;
            while (!done) {
                unsigned vv = stage;
                if (lane < 16)
                    vv = __hip_atomic_load(gflags + lane * 16,
                                           __ATOMIC_RELAXED, __HIP_MEMORY_SCOPE_AGENT);
                done = (__ballot(vv >= stage) == ~0ull);
                if (!done) __builtin_amdgcn_s_sleep(1);
            }
        }
    }
}

extern "C" void kernel_launch(void* const* d_in, const int* in_sizes, int n_in,
                              void* d_out, int out_size, void* d_ws, size_t ws_size,
                              hipStream_t stream)
{
    const float* x   = (const float*)d_in[0];
    const float* WHw = (const float*)d_in[1];
    const float* WHb = (const float*)d_in[2];
    const float* WCw = (const float*)d_in[3];
    const float* WCb = (const float*)d_in[4];
    const float* RHw = (const float*)d_in[5];
    const float* RHb = (const float*)d_in[6];
    const float* RCw = (const float*)d_in[7];
    const float* RCb = (const float*)d_in[8];

    char* ws = (char*)d_ws;
    float*    Pbuf  = (float*)(ws + OFF_P);
    short*    Wt    = (short*)(ws + OFF_W);
    short*    Rt    = (short*)(ws + OFF_R);
    float*    wbc   = (float*)(ws + OFF_WBC);
    float*    rbc   = (float*)(ws + OFF_RBC);
    short*    hbuf  = (short*)(ws + OFF_H);
    unsigned* flags = (unsigned*)(ws + OFF_FLAGS);
    float*    outp  = (float*)d_out;

    rhn_prep<<<15132, 256, 0, stream>>>(WHw, WHb, WCw, WCb, RHw, RHb, RCw, RCb,
                                        Wt, Rt, wbc, rbc, hbuf, flags);
    rhn_proj<<<dim3(16, 512), 256, 0, stream>>>(x, Wt, wbc, Pbuf);

    void* args[] = {&Pbuf, &Rt, &rbc, &hbuf, &flags, &outp};
    hipLaunchCooperativeKernel(reinterpret_cast<void*>(rhn_rec), dim3(64), dim3(256),
                               args, 0, stream);
}